// Round 21
// baseline (276.473 us; speedup 1.0000x reference)
//
#include <hip/hip_runtime.h>

typedef int   v8i    __attribute__((ext_vector_type(8)));
typedef float f32x16 __attribute__((ext_vector_type(16)));

#define NI 256
#define NT 256
#define NL 32
#define NE 128
#define HW 49
#define NEG_INF (-3.0e38f)
#define SCALE1 0x7F7F7F7F   // e8m0 = 127 -> x1.0, all blocks
#define NBLOCKS 1024u

// ws layout (fp8 e4m3, 32x32x64 fragment-linear), validated R15-R19:
//  wsA: frag gw=(i*2+mt)*2+ks, byte j of lane l
//       = img[i, e=ks*64+(l>>5)*32+j, hw=min(mt*32+(l&31),48)]   (2 MB)
//  wsB: frag gw=t*2+ks, byte j of lane l
//       = txt[t, l&31, e=ks*64+(l>>5)*32+j]                      (1 MB)
//  counter: 4 bytes at ws+3MB (zeroed per call via hipMemsetAsync)

__device__ __forceinline__ unsigned char f32_to_e4m3(float f)
{
    unsigned fb = __float_as_uint(f);
    unsigned s  = (fb >> 24) & 0x80;
    int      e  = (int)((fb >> 23) & 0xFF);
    unsigned m  = fb & 0x7FFFFF;
    int ne = e - 120;
    if (ne <= 0)  return (unsigned char)s;
    if (ne > 15) { ne = 15; m = 0x600000; }
    unsigned base = ((unsigned)ne << 3) | (m >> 20);
    unsigned rem  = m & 0xFFFFF;
    if (rem > 0x80000 || (rem == 0x80000 && (base & 1))) base++;   // RNE
    if (base > 0x7E) base = 0x7E;
    return (unsigned char)(s | base);
}

// ---------- fused kernel: consumer-local prep + spin barrier + main ----------
// Grid 1024 x 256, launch_bounds(256,4): ~70 VGPR (R20: 68), 17.4 KB LDS ->
// exactly 4 blocks/CU x 256 CU co-resident (manual capacity arithmetic).
// Phase 1: each block converts the ws slices ITS readers need (XCD-local).
// Barrier: device-scope atomics + s_sleep backoff. Phase 2: R15 main.
__global__ __launch_bounds__(256, 4)
void fused_kernel(const float* __restrict__ img,
                  const float* __restrict__ txt,
                  const int* __restrict__ tlen,
                  const float* __restrict__ nlt,
                  float* __restrict__ out,
                  unsigned char* __restrict__ wsA,
                  unsigned char* __restrict__ wsB,
                  unsigned* __restrict__ cnt)
{
    const int tid  = threadIdx.x;
    const int wave = tid >> 6, lane = tid & 63;
    const int ml   = lane & 31, h = lane >> 5;
    const int bid  = blockIdx.x;
    const int tb   = bid & 15;           // text chunk (16 texts)
    const int ig   = bid >> 4;           // image group (4 images)

    // ======== phase 1a: B slice (1 KB) — chunk tb, written by a reader ========
    {
        int tloc = ig >> 2;              // 0..15: text within chunk
        int qq   = ig & 3;               // quarter of that text's 4 KB
        int t    = tb * 16 + tloc;
        int gw   = t * 2 + (qq >> 1);
        int ks   = gw & 1;
        int l    = tid >> 2;
        int j0   = (qq & 1) * 16 + (tid & 3) * 4;
        const float* p = txt + ((size_t)t * NL + (l & 31)) * NE
                             + ks * 64 + (l >> 5) * 32 + j0;
        float4 f = *(const float4*)p;
        uchar4 u4;
        u4.x = f32_to_e4m3(f.x); u4.y = f32_to_e4m3(f.y);
        u4.z = f32_to_e4m3(f.z); u4.w = f32_to_e4m3(f.w);
        *(uchar4*)(wsB + (size_t)gw * 2048 + l * 32 + j0) = u4;
    }
    // ======== phase 1b: A slice (2 KB) — image-group ig, written locally ======
    {
        int iw  = tb >> 2;               // which of ig's 4 images
        int aq  = tb & 3;                // which (mt,ks) frag-group
        int im2 = ig * 4 + iw;
        int mt  = aq >> 1, ks2 = aq & 1;
        int gw  = (im2 * 2 + mt) * 2 + ks2;
        int l   = tid & 63;
        int j0  = (tid >> 6) * 8;
        int m   = mt * 32 + (l & 31); if (m > HW - 1) m = HW - 1;
        const float* q = img + ((size_t)im2 * NE + ks2 * 64 + (l >> 5) * 32 + j0)
                             * HW + m;
        union { unsigned char b[8]; int2 v; } u;
        #pragma unroll
        for (int j = 0; j < 8; ++j) u.b[j] = f32_to_e4m3(q[j * HW]);
        *(int2*)(wsA + (size_t)gw * 2048 + l * 32 + j0) = u.v;
    }

    // ======== device-scope barrier (all 1024 blocks co-resident) ========
    __threadfence();
    __syncthreads();
    if (tid == 0) {
        atomicAdd(cnt, 1u);
        while (atomicAdd(cnt, 0u) < NBLOCKS) __builtin_amdgcn_s_sleep(64);
    }
    __syncthreads();
    __threadfence();

    // ======== phase 2: MX-fp8 K=64 main (R15, unchanged) ========
    const int im = ig * 4 + wave;        // this wave's image

    __shared__ __align__(16) float colmax[4][16][68];   // ~17.4 KB

    const unsigned char* pa = wsA + (size_t)im * 8192 + lane * 32;
    v8i aA0 = *(const v8i*)(pa);            // mt0 ks0
    v8i aA1 = *(const v8i*)(pa + 2048);     // mt0 ks1
    v8i aB0 = *(const v8i*)(pa + 4096);     // mt1 ks0
    v8i aB1 = *(const v8i*)(pa + 6144);     // mt1 ks1

    const unsigned char* csrc = wsB + (size_t)tb * 16 * 4096 + lane * 32;
#define BFR(t, k) (*(const v8i*)(csrc + (size_t)(t) * 4096 + (k) * 2048))

#define COMPUTE(bk0, bk1, t)                                                \
    {                                                                       \
        f32x16 acc0 = __builtin_amdgcn_mfma_scale_f32_32x32x64_f8f6f4(      \
            aA0, bk0, (f32x16)(0.f), 0, 0, 0, SCALE1, 0, SCALE1);           \
        acc0 = __builtin_amdgcn_mfma_scale_f32_32x32x64_f8f6f4(             \
            aA1, bk1, acc0, 0, 0, 0, SCALE1, 0, SCALE1);                    \
        f32x16 acc1 = __builtin_amdgcn_mfma_scale_f32_32x32x64_f8f6f4(      \
            aB0, bk0, (f32x16)(0.f), 0, 0, 0, SCALE1, 0, SCALE1);           \
        acc1 = __builtin_amdgcn_mfma_scale_f32_32x32x64_f8f6f4(             \
            aB1, bk1, acc1, 0, 0, 0, SCALE1, 0, SCALE1);                    \
        /* C/D: col=lane&31, row r2=(reg&3)+8*(reg>>2)+4*h; acc0: m=r2     \
           (all 16 valid); acc1: m=32+r2 -> regs 0..7, +reg8 iff h==0 */   \
        float t0[8];                                                        \
        _Pragma("unroll")                                                   \
        for (int k = 0; k < 8; ++k) t0[k] = fmaxf(acc0[2*k], acc0[2*k+1]);  \
        float t1[4];                                                        \
        _Pragma("unroll")                                                   \
        for (int k = 0; k < 4; ++k) t1[k] = fmaxf(t0[2*k], t0[2*k+1]);      \
        float a0m = fmaxf(fmaxf(t1[0], t1[1]), fmaxf(t1[2], t1[3]));        \
        float u0[4];                                                        \
        _Pragma("unroll")                                                   \
        for (int k = 0; k < 4; ++k) u0[k] = fmaxf(acc1[2*k], acc1[2*k+1]);  \
        float a1m = fmaxf(fmaxf(u0[0], u0[1]), fmaxf(u0[2], u0[3]));        \
        float ex  = (h == 0) ? acc1[8] : NEG_INF;                           \
        colmax[wave][t][lane] = fmaxf(fmaxf(a0m, a1m), ex);                 \
    }

    v8i c0 = BFR(0, 0), c1 = BFR(0, 1);
    #pragma unroll 1
    for (int it = 0; it < 8; ++it) {
        const int t = 2 * it;
        v8i n0 = BFR(t + 1, 0), n1 = BFR(t + 1, 1);
        COMPUTE(c0, c1, t)
        if (it < 7) { c0 = BFR(t + 2, 0); c1 = BFR(t + 2, 1); }
        COMPUTE(n0, n1, t + 1)
    }
#undef COMPUTE
#undef BFR

    // ---- epilogue: merge h-halves, sum 32 cols, write both mirrors ----
    {
        const float scale = expf(nlt[0]);
        const int t = lane & 15;
        const int q = lane >> 4;
        const float* r0 = &colmax[wave][t][q * 8];        // h-part 0
        const float* r1 = &colmax[wave][t][32 + q * 8];   // h-part 1
        float4 a0 = *(const float4*)(r0 + 0);
        float4 a1 = *(const float4*)(r0 + 4);
        float4 c0 = *(const float4*)(r1 + 0);
        float4 c1 = *(const float4*)(r1 + 4);
        float s = (fmaxf(a0.x, c0.x) + fmaxf(a0.y, c0.y))
                + (fmaxf(a0.z, c0.z) + fmaxf(a0.w, c0.w))
                + (fmaxf(a1.x, c1.x) + fmaxf(a1.y, c1.y))
                + (fmaxf(a1.z, c1.z) + fmaxf(a1.w, c1.w));
        s += __shfl_xor(s, 16);
        s += __shfl_xor(s, 32);
        if (q == 0) {
            int tg = tb * 16 + t;
            float v = s * scale / (float)tlen[tg];
            out[im * NT + tg] = v;              // logits_per_image[i,t]
            out[NI * NT + tg * NI + im] = v;    // logits_per_text[t,i]
        }
    }
}

extern "C" void kernel_launch(void* const* d_in, const int* in_sizes, int n_in,
                              void* d_out, int out_size, void* d_ws, size_t ws_size,
                              hipStream_t stream)
{
    const float* img  = (const float*)d_in[0];
    const float* txt  = (const float*)d_in[1];
    const int*   tlen = (const int*)d_in[2];
    const float* nlt  = (const float*)d_in[3];
    float* out = (float*)d_out;

    unsigned char* wsA = (unsigned char*)d_ws;               // 2 MB
    unsigned char* wsB = wsA + (size_t)2 * 1024 * 1024;      // 1 MB
    unsigned*      cnt = (unsigned*)(wsA + (size_t)3 * 1024 * 1024);

    hipMemsetAsync(cnt, 0, 64, stream);   // reset barrier counter each call
    fused_kernel<<<dim3(1024), dim3(256), 0, stream>>>(
        img, txt, tlen, nlt, out, wsA, wsB, cnt);
}

// Round 22
// 263.773 us; speedup vs baseline: 1.0481x; 1.0481x over previous
//
#include <hip/hip_runtime.h>

typedef int   v8i    __attribute__((ext_vector_type(8)));
typedef float f32x16 __attribute__((ext_vector_type(16)));

#define NI 256
#define NT 256
#define NL 32
#define NE 128
#define HW 49
#define NEG_INF (-3.0e38f)
#define SCALE1 0x7F7F7F7F   // e8m0 = 127 -> x1.0, all blocks
#define NBLOCKS 1024u

// ws layout (fp8 e4m3, 32x32x64 fragment-linear), validated R15-R21:
//  wsA: frag gw=(i*2+mt)*2+ks, byte j of lane l
//       = img[i, e=ks*64+(l>>5)*32+j, hw=min(mt*32+(l&31),48)]   (2 MB)
//  wsB: frag gw=t*2+ks, byte j of lane l
//       = txt[t, l&31, e=ks*64+(l>>5)*32+j]                      (1 MB)
//  counter: 4 bytes at ws+3MB (zeroed per call via hipMemsetAsync)

__device__ __forceinline__ unsigned char f32_to_e4m3(float f)
{
    unsigned fb = __float_as_uint(f);
    unsigned s  = (fb >> 24) & 0x80;
    int      e  = (int)((fb >> 23) & 0xFF);
    unsigned m  = fb & 0x7FFFFF;
    int ne = e - 120;
    if (ne <= 0)  return (unsigned char)s;
    if (ne > 15) { ne = 15; m = 0x600000; }
    unsigned base = ((unsigned)ne << 3) | (m >> 20);
    unsigned rem  = m & 0xFFFFF;
    if (rem > 0x80000 || (rem == 0x80000 && (base & 1))) base++;   // RNE
    if (base > 0x7E) base = 0x7E;
    return (unsigned char)(s | base);
}

// ---------- fused kernel: consumer-local prep + arrive/load-poll barrier ----------
// Grid 1024 x 256, launch_bounds(256,4): 56 VGPR (R21 measured), 17.4 KB LDS
// -> 4 blocks/CU x 256 CU co-resident (R21 verified: occupancy 47%, correct).
// R21's bug: polling with atomicAdd(cnt,0) = serialized device-scope RMW x
// 1024 pollers = ~250us. Fix: ONE RMW at arrival; poll with agent-scope
// atomic LOAD (concurrent, no serialization) + s_sleep backoff.
__global__ __launch_bounds__(256, 4)
void fused_kernel(const float* __restrict__ img,
                  const float* __restrict__ txt,
                  const int* __restrict__ tlen,
                  const float* __restrict__ nlt,
                  float* __restrict__ out,
                  unsigned char* __restrict__ wsA,
                  unsigned char* __restrict__ wsB,
                  unsigned* __restrict__ cnt)
{
    const int tid  = threadIdx.x;
    const int wave = tid >> 6, lane = tid & 63;
    const int ml   = lane & 31, h = lane >> 5;
    const int bid  = blockIdx.x;
    const int tb   = bid & 15;           // text chunk (16 texts)
    const int ig   = bid >> 4;           // image group (4 images)

    // ======== phase 1a: B slice (1 KB) — chunk tb, written by a reader ========
    {
        int tloc = ig >> 2;              // 0..15: text within chunk
        int qq   = ig & 3;               // quarter of that text's 4 KB
        int t    = tb * 16 + tloc;
        int gw   = t * 2 + (qq >> 1);
        int ks   = gw & 1;
        int l    = tid >> 2;
        int j0   = (qq & 1) * 16 + (tid & 3) * 4;
        const float* p = txt + ((size_t)t * NL + (l & 31)) * NE
                             + ks * 64 + (l >> 5) * 32 + j0;
        float4 f = *(const float4*)p;
        uchar4 u4;
        u4.x = f32_to_e4m3(f.x); u4.y = f32_to_e4m3(f.y);
        u4.z = f32_to_e4m3(f.z); u4.w = f32_to_e4m3(f.w);
        *(uchar4*)(wsB + (size_t)gw * 2048 + l * 32 + j0) = u4;
    }
    // ======== phase 1b: A slice (2 KB) — image-group ig, written locally ======
    {
        int iw  = tb >> 2;               // which of ig's 4 images
        int aq  = tb & 3;                // which (mt,ks) frag-group
        int im2 = ig * 4 + iw;
        int mt  = aq >> 1, ks2 = aq & 1;
        int gw  = (im2 * 2 + mt) * 2 + ks2;
        int l   = tid & 63;
        int j0  = (tid >> 6) * 8;
        int m   = mt * 32 + (l & 31); if (m > HW - 1) m = HW - 1;
        const float* q = img + ((size_t)im2 * NE + ks2 * 64 + (l >> 5) * 32 + j0)
                             * HW + m;
        union { unsigned char b[8]; int2 v; } u;
        #pragma unroll
        for (int j = 0; j < 8; ++j) u.b[j] = f32_to_e4m3(q[j * HW]);
        *(int2*)(wsA + (size_t)gw * 2048 + l * 32 + j0) = u.v;
    }

    // ======== device-scope barrier: 1 RMW arrive + load-poll wait ========
    __threadfence();                         // release ws writes
    __syncthreads();
    if (tid == 0) {
        atomicAdd(cnt, 1u);                  // single RMW per block
        while (__hip_atomic_load(cnt, __ATOMIC_RELAXED,
                                 __HIP_MEMORY_SCOPE_AGENT) < NBLOCKS)
            __builtin_amdgcn_s_sleep(2);     // concurrent loads: no serialization
    }
    __syncthreads();
    __threadfence();                         // acquire

    // ======== phase 2: MX-fp8 K=64 main (R15, unchanged) ========
    const int im = ig * 4 + wave;        // this wave's image

    __shared__ __align__(16) float colmax[4][16][68];   // ~17.4 KB

    const unsigned char* pa = wsA + (size_t)im * 8192 + lane * 32;
    v8i aA0 = *(const v8i*)(pa);            // mt0 ks0
    v8i aA1 = *(const v8i*)(pa + 2048);     // mt0 ks1
    v8i aB0 = *(const v8i*)(pa + 4096);     // mt1 ks0
    v8i aB1 = *(const v8i*)(pa + 6144);     // mt1 ks1

    const unsigned char* csrc = wsB + (size_t)tb * 16 * 4096 + lane * 32;
#define BFR(t, k) (*(const v8i*)(csrc + (size_t)(t) * 4096 + (k) * 2048))

#define COMPUTE(bk0, bk1, t)                                                \
    {                                                                       \
        f32x16 acc0 = __builtin_amdgcn_mfma_scale_f32_32x32x64_f8f6f4(      \
            aA0, bk0, (f32x16)(0.f), 0, 0, 0, SCALE1, 0, SCALE1);           \
        acc0 = __builtin_amdgcn_mfma_scale_f32_32x32x64_f8f6f4(             \
            aA1, bk1, acc0, 0, 0, 0, SCALE1, 0, SCALE1);                    \
        f32x16 acc1 = __builtin_amdgcn_mfma_scale_f32_32x32x64_f8f6f4(      \
            aB0, bk0, (f32x16)(0.f), 0, 0, 0, SCALE1, 0, SCALE1);           \
        acc1 = __builtin_amdgcn_mfma_scale_f32_32x32x64_f8f6f4(             \
            aB1, bk1, acc1, 0, 0, 0, SCALE1, 0, SCALE1);                    \
        /* C/D: col=lane&31, row r2=(reg&3)+8*(reg>>2)+4*h; acc0: m=r2     \
           (all 16 valid); acc1: m=32+r2 -> regs 0..7, +reg8 iff h==0 */   \
        float t0[8];                                                        \
        _Pragma("unroll")                                                   \
        for (int k = 0; k < 8; ++k) t0[k] = fmaxf(acc0[2*k], acc0[2*k+1]);  \
        float t1[4];                                                        \
        _Pragma("unroll")                                                   \
        for (int k = 0; k < 4; ++k) t1[k] = fmaxf(t0[2*k], t0[2*k+1]);      \
        float a0m = fmaxf(fmaxf(t1[0], t1[1]), fmaxf(t1[2], t1[3]));        \
        float u0[4];                                                        \
        _Pragma("unroll")                                                   \
        for (int k = 0; k < 4; ++k) u0[k] = fmaxf(acc1[2*k], acc1[2*k+1]);  \
        float a1m = fmaxf(fmaxf(u0[0], u0[1]), fmaxf(u0[2], u0[3]));        \
        float ex  = (h == 0) ? acc1[8] : NEG_INF;                           \
        colmax[wave][t][lane] = fmaxf(fmaxf(a0m, a1m), ex);                 \
    }

    v8i c0 = BFR(0, 0), c1 = BFR(0, 1);
    #pragma unroll 1
    for (int it = 0; it < 8; ++it) {
        const int t = 2 * it;
        v8i n0 = BFR(t + 1, 0), n1 = BFR(t + 1, 1);
        COMPUTE(c0, c1, t)
        if (it < 7) { c0 = BFR(t + 2, 0); c1 = BFR(t + 2, 1); }
        COMPUTE(n0, n1, t + 1)
    }
#undef COMPUTE
#undef BFR

    // ---- epilogue: merge h-halves, sum 32 cols, write both mirrors ----
    {
        const float scale = expf(nlt[0]);
        const int t = lane & 15;
        const int q = lane >> 4;
        const float* r0 = &colmax[wave][t][q * 8];        // h-part 0
        const float* r1 = &colmax[wave][t][32 + q * 8];   // h-part 1
        float4 a0 = *(const float4*)(r0 + 0);
        float4 a1 = *(const float4*)(r0 + 4);
        float4 c0 = *(const float4*)(r1 + 0);
        float4 c1 = *(const float4*)(r1 + 4);
        float s = (fmaxf(a0.x, c0.x) + fmaxf(a0.y, c0.y))
                + (fmaxf(a0.z, c0.z) + fmaxf(a0.w, c0.w))
                + (fmaxf(a1.x, c1.x) + fmaxf(a1.y, c1.y))
                + (fmaxf(a1.z, c1.z) + fmaxf(a1.w, c1.w));
        s += __shfl_xor(s, 16);
        s += __shfl_xor(s, 32);
        if (q == 0) {
            int tg = tb * 16 + t;
            float v = s * scale / (float)tlen[tg];
            out[im * NT + tg] = v;              // logits_per_image[i,t]
            out[NI * NT + tg * NI + im] = v;    // logits_per_text[t,i]
        }
    }
}

extern "C" void kernel_launch(void* const* d_in, const int* in_sizes, int n_in,
                              void* d_out, int out_size, void* d_ws, size_t ws_size,
                              hipStream_t stream)
{
    const float* img  = (const float*)d_in[0];
    const float* txt  = (const float*)d_in[1];
    const int*   tlen = (const int*)d_in[2];
    const float* nlt  = (const float*)d_in[3];
    float* out = (float*)d_out;

    unsigned char* wsA = (unsigned char*)d_ws;               // 2 MB
    unsigned char* wsB = wsA + (size_t)2 * 1024 * 1024;      // 1 MB
    unsigned*      cnt = (unsigned*)(wsA + (size_t)3 * 1024 * 1024);

    hipMemsetAsync(cnt, 0, 64, stream);   // reset barrier counter each call
    fused_kernel<<<dim3(1024), dim3(256), 0, stream>>>(
        img, txt, tlen, nlt, out, wsA, wsB, cnt);
}

// Round 23
// 144.522 us; speedup vs baseline: 1.9130x; 1.8251x over previous
//
#include <hip/hip_runtime.h>

typedef int   v8i    __attribute__((ext_vector_type(8)));
typedef float f32x16 __attribute__((ext_vector_type(16)));

#define NI 256
#define NT 256
#define NL 32
#define NE 128
#define HW 49
#define NEG_INF (-3.0e38f)
#define SCALE1 0x7F7F7F7F   // e8m0 = 127 -> x1.0, all blocks
#define NBLOCKS 512u

// ws layout (fp8 e4m3, 32x32x64 fragment-linear), validated R15-R22:
//  wsA: frag gw=(i*2+mt)*2+ks, byte j of lane l
//       = img[i, e=ks*64+(l>>5)*32+j, hw=min(mt*32+(l&31),48)]   (2 MB)
//  wsB: frag gw=t*2+ks, byte j of lane l
//       = txt[t, l&31, e=ks*64+(l>>5)*32+j]                      (1 MB)
//  counter: 4 bytes at ws+3MB (zeroed per call via hipMemsetAsync)

__device__ __forceinline__ unsigned char f32_to_e4m3(float f)
{
    unsigned fb = __float_as_uint(f);
    unsigned s  = (fb >> 24) & 0x80;
    int      e  = (int)((fb >> 23) & 0xFF);
    unsigned m  = fb & 0x7FFFFF;
    int ne = e - 120;
    if (ne <= 0)  return (unsigned char)s;
    if (ne > 15) { ne = 15; m = 0x600000; }
    unsigned base = ((unsigned)ne << 3) | (m >> 20);
    unsigned rem  = m & 0xFFFFF;
    if (rem > 0x80000 || (rem == 0x80000 && (base & 1))) base++;   // RNE
    if (base > 0x7E) base = 0x7E;
    return (unsigned char)(s | base);
}

// ---------- fused kernel, grid 512 (2 blocks/CU: residency slack) ----------
// R21/R22's ~264us barrier = timeslice quantum: at grid 1024 a few blocks
// were NOT co-resident (occupancy 47% < 50%), spinners starved them until
// preemption. Grid 512 = 2 blocks/CU needs 1/4 of every resource -> all
// co-resident with margin. Each block runs TWO work-units (bid, bid+512);
// both share the same text chunk (512 % 16 == 0) so B is warm for unit 2.
__global__ __launch_bounds__(256, 4)
void fused_kernel(const float* __restrict__ img,
                  const float* __restrict__ txt,
                  const int* __restrict__ tlen,
                  const float* __restrict__ nlt,
                  float* __restrict__ out,
                  unsigned char* __restrict__ wsA,
                  unsigned char* __restrict__ wsB,
                  unsigned* __restrict__ cnt)
{
    const int tid  = threadIdx.x;
    const int wave = tid >> 6, lane = tid & 63;
    const int h    = lane >> 5;
    const int bid  = blockIdx.x;

    // ======== phase 1: convert both units' consumer-local ws slices ========
    #pragma unroll 1
    for (int u = 0; u < 2; ++u) {
        const int unit = bid + u * 512;      // 0..1023
        const int tb   = unit & 15;
        const int ig   = unit >> 4;
        // -- B slice (1 KB): chunk tb --
        {
            int tloc = ig >> 2;              // text within chunk
            int qq   = ig & 3;               // quarter of that text's 4 KB
            int t    = tb * 16 + tloc;
            int gw   = t * 2 + (qq >> 1);
            int ks   = gw & 1;
            int l    = tid >> 2;
            int j0   = (qq & 1) * 16 + (tid & 3) * 4;
            const float* p = txt + ((size_t)t * NL + (l & 31)) * NE
                                 + ks * 64 + (l >> 5) * 32 + j0;
            float4 f = *(const float4*)p;
            uchar4 u4;
            u4.x = f32_to_e4m3(f.x); u4.y = f32_to_e4m3(f.y);
            u4.z = f32_to_e4m3(f.z); u4.w = f32_to_e4m3(f.w);
            *(uchar4*)(wsB + (size_t)gw * 2048 + l * 32 + j0) = u4;
        }
        // -- A slice (2 KB): image-group ig --
        {
            int iw  = tb >> 2;               // which of ig's 4 images
            int aq  = tb & 3;                // which (mt,ks) frag-group
            int im2 = ig * 4 + iw;
            int mt  = aq >> 1, ks2 = aq & 1;
            int gw  = (im2 * 2 + mt) * 2 + ks2;
            int l   = tid & 63;
            int j0  = (tid >> 6) * 8;
            int m   = mt * 32 + (l & 31); if (m > HW - 1) m = HW - 1;
            const float* q = img
                + ((size_t)im2 * NE + ks2 * 64 + (l >> 5) * 32 + j0) * HW + m;
            union { unsigned char b[8]; int2 v; } uu;
            #pragma unroll
            for (int j = 0; j < 8; ++j) uu.b[j] = f32_to_e4m3(q[j * HW]);
            *(int2*)(wsA + (size_t)gw * 2048 + l * 32 + j0) = uu.v;
        }
    }

    // ======== device-scope barrier: 1 RMW arrive + load-poll wait ========
    __threadfence();                         // release ws writes
    __syncthreads();
    if (tid == 0) {
        atomicAdd(cnt, 1u);                  // single RMW per block
        while (__hip_atomic_load(cnt, __ATOMIC_RELAXED,
                                 __HIP_MEMORY_SCOPE_AGENT) < NBLOCKS)
            __builtin_amdgcn_s_sleep(16);
    }
    __syncthreads();
    __threadfence();                         // acquire

    // ======== phase 2: MX-fp8 K=64 main (R15), both units sequentially ======
    __shared__ __align__(16) float colmax[4][16][68];   // ~17.4 KB, reused

    #pragma unroll 1
    for (int u = 0; u < 2; ++u) {
        const int unit = bid + u * 512;
        const int tb   = unit & 15;
        const int ig   = unit >> 4;
        const int im   = ig * 4 + wave;      // this wave's image

        const unsigned char* pa = wsA + (size_t)im * 8192 + lane * 32;
        v8i aA0 = *(const v8i*)(pa);            // mt0 ks0
        v8i aA1 = *(const v8i*)(pa + 2048);     // mt0 ks1
        v8i aB0 = *(const v8i*)(pa + 4096);     // mt1 ks0
        v8i aB1 = *(const v8i*)(pa + 6144);     // mt1 ks1

        const unsigned char* csrc = wsB + (size_t)tb * 16 * 4096 + lane * 32;
#define BFR(t, k) (*(const v8i*)(csrc + (size_t)(t) * 4096 + (k) * 2048))

#define COMPUTE(bk0, bk1, t)                                                \
    {                                                                       \
        f32x16 acc0 = __builtin_amdgcn_mfma_scale_f32_32x32x64_f8f6f4(      \
            aA0, bk0, (f32x16)(0.f), 0, 0, 0, SCALE1, 0, SCALE1);           \
        acc0 = __builtin_amdgcn_mfma_scale_f32_32x32x64_f8f6f4(             \
            aA1, bk1, acc0, 0, 0, 0, SCALE1, 0, SCALE1);                    \
        f32x16 acc1 = __builtin_amdgcn_mfma_scale_f32_32x32x64_f8f6f4(      \
            aB0, bk0, (f32x16)(0.f), 0, 0, 0, SCALE1, 0, SCALE1);           \
        acc1 = __builtin_amdgcn_mfma_scale_f32_32x32x64_f8f6f4(             \
            aB1, bk1, acc1, 0, 0, 0, SCALE1, 0, SCALE1);                    \
        /* C/D: col=lane&31, row r2=(reg&3)+8*(reg>>2)+4*h; acc0: m=r2     \
           (all 16 valid); acc1: m=32+r2 -> regs 0..7, +reg8 iff h==0 */   \
        float t0[8];                                                        \
        _Pragma("unroll")                                                   \
        for (int k = 0; k < 8; ++k) t0[k] = fmaxf(acc0[2*k], acc0[2*k+1]);  \
        float t1[4];                                                        \
        _Pragma("unroll")                                                   \
        for (int k = 0; k < 4; ++k) t1[k] = fmaxf(t0[2*k], t0[2*k+1]);      \
        float a0m = fmaxf(fmaxf(t1[0], t1[1]), fmaxf(t1[2], t1[3]));        \
        float u0[4];                                                        \
        _Pragma("unroll")                                                   \
        for (int k = 0; k < 4; ++k) u0[k] = fmaxf(acc1[2*k], acc1[2*k+1]);  \
        float a1m = fmaxf(fmaxf(u0[0], u0[1]), fmaxf(u0[2], u0[3]));        \
        float ex  = (h == 0) ? acc1[8] : NEG_INF;                           \
        colmax[wave][t][lane] = fmaxf(fmaxf(a0m, a1m), ex);                 \
    }

        v8i c0 = BFR(0, 0), c1 = BFR(0, 1);
        #pragma unroll 1
        for (int it = 0; it < 8; ++it) {
            const int t = 2 * it;
            v8i n0 = BFR(t + 1, 0), n1 = BFR(t + 1, 1);
            COMPUTE(c0, c1, t)
            if (it < 7) { c0 = BFR(t + 2, 0); c1 = BFR(t + 2, 1); }
            COMPUTE(n0, n1, t + 1)
        }
#undef COMPUTE
#undef BFR

        // ---- epilogue: merge h-halves, sum 32 cols, write both mirrors ----
        {
            const float scale = expf(nlt[0]);
            const int t = lane & 15;
            const int q = lane >> 4;
            const float* r0 = &colmax[wave][t][q * 8];        // h-part 0
            const float* r1 = &colmax[wave][t][32 + q * 8];   // h-part 1
            float4 a0 = *(const float4*)(r0 + 0);
            float4 a1 = *(const float4*)(r0 + 4);
            float4 c0 = *(const float4*)(r1 + 0);
            float4 c1 = *(const float4*)(r1 + 4);
            float s = (fmaxf(a0.x, c0.x) + fmaxf(a0.y, c0.y))
                    + (fmaxf(a0.z, c0.z) + fmaxf(a0.w, c0.w))
                    + (fmaxf(a1.x, c1.x) + fmaxf(a1.y, c1.y))
                    + (fmaxf(a1.z, c1.z) + fmaxf(a1.w, c1.w));
            s += __shfl_xor(s, 16);
            s += __shfl_xor(s, 32);
            if (q == 0) {
                int tg = tb * 16 + t;
                float v = s * scale / (float)tlen[tg];
                out[im * NT + tg] = v;              // logits_per_image[i,t]
                out[NI * NT + tg * NI + im] = v;    // logits_per_text[t,i]
            }
        }
    }
}

extern "C" void kernel_launch(void* const* d_in, const int* in_sizes, int n_in,
                              void* d_out, int out_size, void* d_ws, size_t ws_size,
                              hipStream_t stream)
{
    const float* img  = (const float*)d_in[0];
    const float* txt  = (const float*)d_in[1];
    const int*   tlen = (const int*)d_in[2];
    const float* nlt  = (const float*)d_in[3];
    float* out = (float*)d_out;

    unsigned char* wsA = (unsigned char*)d_ws;               // 2 MB
    unsigned char* wsB = wsA + (size_t)2 * 1024 * 1024;      // 1 MB
    unsigned*      cnt = (unsigned*)(wsA + (size_t)3 * 1024 * 1024);

    hipMemsetAsync(cnt, 0, 64, stream);   // reset barrier counter each call
    fused_kernel<<<dim3(512), dim3(256), 0, stream>>>(
        img, txt, tlen, nlt, out, wsA, wsB, cnt);
}

// Round 24
// 27.368 us; speedup vs baseline: 10.1022x; 5.2808x over previous
//
#include <hip/hip_runtime.h>

typedef int   v8i    __attribute__((ext_vector_type(8)));
typedef float f32x16 __attribute__((ext_vector_type(16)));

#define NI 256
#define NT 256
#define NL 32
#define NE 128
#define HW 49
#define NEG_INF (-3.0e38f)
#define SCALE1 0x7F7F7F7F   // e8m0 = 127 -> x1.0, all blocks

// ws layout (fp8 e4m3, 32x32x64 fragment-linear):
//  wsA: frag gw=(i*2+mt)*2+ks; lane l holds 32B at gw*2048 + l*32
//       byte j = img[i, e=ks*64+(l>>5)*32+j, hw=min(mt*32+(l&31),48)]  (2 MB)
//  wsB (SPLIT-16B, new): frag gw=t*2+ks; lane l's bytes 0-15 at
//       gw*2048 + l*16, bytes 16-31 at gw*2048 + 1024 + l*16
//       byte j = txt[t, l&31, e=ks*64+(l>>5)*32+j]                     (1 MB)
//  Split-16B makes LDS ds_read_b128 lane-stride 16 = conflict-free.
//  A and B use the SAME k<->(lane,byte) map -> k-permutation cancels.

__device__ __forceinline__ unsigned char f32_to_e4m3(float f)
{
    unsigned fb = __float_as_uint(f);
    unsigned s  = (fb >> 24) & 0x80;
    int      e  = (int)((fb >> 23) & 0xFF);
    unsigned m  = fb & 0x7FFFFF;
    int ne = e - 120;
    if (ne <= 0)  return (unsigned char)s;
    if (ne > 15) { ne = 15; m = 0x600000; }
    unsigned base = ((unsigned)ne << 3) | (m >> 20);
    unsigned rem  = m & 0xFFFFF;
    if (rem > 0x80000 || (rem == 0x80000 && (base & 1))) base++;   // RNE
    if (base > 0x7E) base = 0x7E;
    return (unsigned char)(s | base);
}

// ---------- pre-kernel: whole-chip spread (1280 blocks), R19 + split-16B B ----------
__global__ __launch_bounds__(256, 4)
void prep_kernel(const float* __restrict__ img,
                 const float* __restrict__ txt,
                 unsigned char* __restrict__ wsA,
                 unsigned char* __restrict__ wsB)
{
    const int tid  = threadIdx.x;
    const int wave = tid >> 6, lane = tid & 63;
    const int ml   = lane & 31, h = lane >> 5;
    const int bid  = blockIdx.x;
    if (bid < 1024) {                       // A-part: one frag-group per block
        int gw = bid;                       // (i, mt, ks)
        int i  = gw >> 2, mt = (gw >> 1) & 1, ks = gw & 1;
        int m  = mt * 32 + ml; if (m > HW - 1) m = HW - 1;
        int e0 = ks * 64 + h * 32 + wave * 8;     // this wave's 8-e slice
        const float* p = img + ((size_t)i * NE + e0) * HW + m;
        union { unsigned char b[8]; int2 v; } u;
        #pragma unroll
        for (int j = 0; j < 8; ++j) u.b[j] = f32_to_e4m3(p[j * HW]);
        *(int2*)(wsA + (size_t)gw * 2048 + lane * 32 + wave * 8) = u.v;
    } else {                                // B-part: 2 frag-groups per block
        int bb = bid - 1024;                // 0..255
        int gw = bb * 2 + (wave >> 1);      // (t, ks)
        int eh = wave & 1;                  // which 16B half of the lane's 32B
        int t  = gw >> 1, ks = gw & 1;
        int e0 = ks * 64 + h * 32 + eh * 16;
        const float* p = txt + ((size_t)t * NL + ml) * NE + e0;
        union { unsigned char b[16]; int4 v; } u;
        #pragma unroll
        for (int q = 0; q < 4; ++q) {
            float4 f = *(const float4*)(p + q * 4);
            u.b[q*4+0] = f32_to_e4m3(f.x); u.b[q*4+1] = f32_to_e4m3(f.y);
            u.b[q*4+2] = f32_to_e4m3(f.z); u.b[q*4+3] = f32_to_e4m3(f.w);
        }
        // split-16B: half eh of lane's 32B lives at eh*1024 + lane*16
        *(int4*)(wsB + (size_t)gw * 2048 + eh * 1024 + lane * 16) = u.v;
    }
}

#define GLDS(gp, lp) __builtin_amdgcn_global_load_lds(                     \
        (const __attribute__((address_space(1))) void*)(gp),               \
        (__attribute__((address_space(3))) void*)(lp), 16, 0, 0)

// ---------- main kernel: B staged in LDS (L2 traffic 268->67 MB) ----------
// Grid 1024 = 64 ig x 16 tb, 4 blocks/CU (LDS exactly 40 KB). Two stage
// rounds of 8 texts (32 KB via global_load_lds), 4 __syncthreads total;
// compute is barrier-free: per text 4 conflict-free ds_read_b128 + 4
// mfma_scale + fmax tree + shfl_xor(32) merge -> colmax.
__global__ __launch_bounds__(256, 4)
void clip_match_kernel(const unsigned char* __restrict__ wsA,
                       const unsigned char* __restrict__ wsB,
                       const int* __restrict__ tlen,
                       const float* __restrict__ nlt,
                       float* __restrict__ out)
{
    const int tid  = threadIdx.x;
    const int wave = tid >> 6, lane = tid & 63;
    const int ml   = lane & 31, h = lane >> 5;
    const int tb   = blockIdx.x & 15;    // text chunk (16 texts)
    const int ig   = blockIdx.x >> 4;    // image group (4 images)
    const int im   = ig * 4 + wave;      // this wave's image

    __shared__ __align__(16) unsigned char bstage[32768];   // 8 texts
    __shared__ __align__(16) float colmax[4][16][32];       // 8 KB
    // total LDS = 40960 B exactly -> 4 blocks/CU

    // ---- A fragments: 4 x v8i = 32 VGPR, direct from wsA (L2) ----
    const unsigned char* pa = wsA + (size_t)im * 8192 + lane * 32;
    v8i aA0 = *(const v8i*)(pa);            // mt0 ks0
    v8i aA1 = *(const v8i*)(pa + 2048);     // mt0 ks1
    v8i aB0 = *(const v8i*)(pa + 4096);     // mt1 ks0
    v8i aB1 = *(const v8i*)(pa + 6144);     // mt1 ks1

    const unsigned char* csrc = wsB + (size_t)tb * 16 * 4096;   // chunk base

#define COMPUTE(bk0, bk1, t)                                                \
    {                                                                       \
        f32x16 acc0 = __builtin_amdgcn_mfma_scale_f32_32x32x64_f8f6f4(      \
            aA0, bk0, (f32x16)(0.f), 0, 0, 0, SCALE1, 0, SCALE1);           \
        acc0 = __builtin_amdgcn_mfma_scale_f32_32x32x64_f8f6f4(             \
            aA1, bk1, acc0, 0, 0, 0, SCALE1, 0, SCALE1);                    \
        f32x16 acc1 = __builtin_amdgcn_mfma_scale_f32_32x32x64_f8f6f4(      \
            aB0, bk0, (f32x16)(0.f), 0, 0, 0, SCALE1, 0, SCALE1);           \
        acc1 = __builtin_amdgcn_mfma_scale_f32_32x32x64_f8f6f4(             \
            aB1, bk1, acc1, 0, 0, 0, SCALE1, 0, SCALE1);                    \
        /* C/D: col=lane&31, row r2=(reg&3)+8*(reg>>2)+4*h; acc0: m=r2     \
           (all 16 valid); acc1: m=32+r2 -> regs 0..7, +reg8 iff h==0 */   \
        float t0[8];                                                        \
        _Pragma("unroll")                                                   \
        for (int k = 0; k < 8; ++k) t0[k] = fmaxf(acc0[2*k], acc0[2*k+1]);  \
        float t1[4];                                                        \
        _Pragma("unroll")                                                   \
        for (int k = 0; k < 4; ++k) t1[k] = fmaxf(t0[2*k], t0[2*k+1]);      \
        float a0m = fmaxf(fmaxf(t1[0], t1[1]), fmaxf(t1[2], t1[3]));        \
        float u0[4];                                                        \
        _Pragma("unroll")                                                   \
        for (int k = 0; k < 4; ++k) u0[k] = fmaxf(acc1[2*k], acc1[2*k+1]);  \
        float a1m = fmaxf(fmaxf(u0[0], u0[1]), fmaxf(u0[2], u0[3]));        \
        float ex  = (h == 0) ? acc1[8] : NEG_INF;                           \
        float cm  = fmaxf(fmaxf(a0m, a1m), ex);                             \
        cm = fmaxf(cm, __shfl_xor(cm, 32));        /* merge h-halves */     \
        if (h == 0) colmax[wave][t][ml] = cm;                               \
    }

    #pragma unroll 1
    for (int r = 0; r < 2; ++r) {
        // ---- stage 8 texts (32 KB) into LDS via global_load_lds ----
        {
            const unsigned char* src = csrc + r * 32768;
            #pragma unroll
            for (int it = 0; it < 8; ++it)
                GLDS(src + it * 4096 + tid * 16, bstage + it * 4096 + tid * 16);
        }
        asm volatile("s_waitcnt vmcnt(0)" ::: "memory");
        __builtin_amdgcn_sched_barrier(0);
        __syncthreads();

        // ---- compute 8 texts from LDS (conflict-free b128 reads) ----
        #pragma unroll
        for (int ts = 0; ts < 8; ++ts) {
            const int t = r * 8 + ts;
            union { int4 q[2]; v8i v; } b0, b1;
            const unsigned char* base = bstage + ts * 4096 + lane * 16;
            b0.q[0] = *(const int4*)(base);               // k0 lo
            b0.q[1] = *(const int4*)(base + 1024);        // k0 hi
            b1.q[0] = *(const int4*)(base + 2048);        // k1 lo
            b1.q[1] = *(const int4*)(base + 3072);        // k1 hi
            COMPUTE(b0.v, b1.v, t)
        }
        __syncthreads();   // all waves done with bstage before restage
    }

    // ---- epilogue: sum 32 cols per text; write both mirrors ----
    {
        const float scale = expf(nlt[0]);
        const int t = lane & 15;             // text within chunk
        const int q = lane >> 4;             // col octet 0..3
        const float* row = &colmax[wave][t][q * 8];
        float4 a0 = *(const float4*)(row + 0);
        float4 a1 = *(const float4*)(row + 4);
        float s = ((a0.x + a0.y) + (a0.z + a0.w))
                + ((a1.x + a1.y) + (a1.z + a1.w));
        s += __shfl_xor(s, 16);
        s += __shfl_xor(s, 32);              // all 32 cols
        if (q == 0) {
            int tg = tb * 16 + t;
            float v = s * scale / (float)tlen[tg];
            out[im * NT + tg] = v;              // logits_per_image[i,t]
            out[NI * NT + tg * NI + im] = v;    // logits_per_text[t,i]
        }
    }
}

extern "C" void kernel_launch(void* const* d_in, const int* in_sizes, int n_in,
                              void* d_out, int out_size, void* d_ws, size_t ws_size,
                              hipStream_t stream)
{
    const float* img  = (const float*)d_in[0];
    const float* txt  = (const float*)d_in[1];
    const int*   tlen = (const int*)d_in[2];
    const float* nlt  = (const float*)d_in[3];
    float* out = (float*)d_out;

    unsigned char* wsA = (unsigned char*)d_ws;               // 2 MB
    unsigned char* wsB = wsA + (size_t)2 * 1024 * 1024;      // 1 MB

    prep_kernel<<<dim3(1280), dim3(256), 0, stream>>>(img, txt, wsA, wsB);
    clip_match_kernel<<<dim3(1024), dim3(256), 0, stream>>>(wsA, wsB, tlen, nlt, out);
}